// Round 3
// baseline (9287.926 us; speedup 1.0000x reference)
//
#include <hip/hip_runtime.h>
#include <math.h>
#include <stdint.h>

#define NLAT 128
#define NLON 256
#define PI_F 3.14159265358979323846f
#define TWO_PI_F 6.28318530717958647692f

typedef unsigned short u16;

__device__ __forceinline__ u16 f2b(float f) {          // fp32 -> bf16 RNE
    union { float f; uint32_t u; } v; v.f = f;
    uint32_t r = v.u + 0x7fffu + ((v.u >> 16) & 1u);
    return (u16)(r >> 16);
}
__device__ __forceinline__ float b2f(u16 u) {          // bf16 -> fp32 exact
    union { uint32_t u; float f; } v; v.u = ((uint32_t)u) << 16;
    return v.f;
}
__device__ __forceinline__ ushort4 pack4(float a, float b, float c, float d) {
    ushort4 r; r.x = f2b(a); r.y = f2b(b); r.z = f2b(c); r.w = f2b(d); return r;
}

__device__ __forceinline__ float gelu_tanh(float x) {
    float x3 = x * x * x;
    return 0.5f * x * (1.0f + tanhf(0.7978845608028654f * (x + 0.044715f * x3)));
}
__device__ __forceinline__ float leaky(float x) { return x >= 0.0f ? x : 0.2f * x; }

__device__ __forceinline__ float lat_weight(const float* __restrict__ lat, int i, int n) {
    float w = cosf(lat[i]);
    if ((i == 0 || i == n - 1) && w < 0.001f) {
        float dlat = lat[1] - lat[0];
        float s = sinf(dlat * 0.25f);
        w = s * s / sinf(dlat * 0.5f);  // POLAR_EPS = 1
    }
    return w;
}

// ---------------------------------------------------------------- K1: cm MLP (per batch)
// 32768 rows of u[row][256]; t = gelu(u@W1+b1)[1536]; out = t@W2+b2 [1024]
// -> v bf16 (512) | uu bf16 (256) | uskip fp32 (256, into d_out half)
__global__ __launch_bounds__(256) void cm_mlp_kernel(
    const float* __restrict__ u, const float* __restrict__ w1, const float* __restrict__ b1,
    const float* __restrict__ w2, const float* __restrict__ b2,
    u16* __restrict__ v, u16* __restrict__ uu, float* __restrict__ uskip)
{
    __shared__ __align__(16) float su[16][256];
    __shared__ __align__(16) float st[16][512];
    const int t = threadIdx.x;
    const int row0 = blockIdx.x * 16;

    #pragma unroll
    for (int r = 0; r < 16; ++r) su[r][t] = u[(size_t)(row0 + r) * 256 + t];

    float acc[16][4];
    #pragma unroll
    for (int r = 0; r < 16; ++r) { acc[r][0] = acc[r][1] = acc[r][2] = acc[r][3] = 0.f; }
    const int k0 = t * 4;

    for (int jj = 0; jj < 3; ++jj) {
        __syncthreads();   // iter0: su ready; later: previous st fully consumed
        const int ja = jj * 512 + t;
        const int jb = ja + 256;
        float accA[16], accB[16];
        #pragma unroll
        for (int r = 0; r < 16; ++r) { accA[r] = 0.f; accB[r] = 0.f; }
        const float* w1p = w1 + ja;
        #pragma unroll 2
        for (int i = 0; i < 256; ++i) {
            float wa = w1p[(size_t)i * 1536];
            float wb = w1p[(size_t)i * 1536 + 256];
            #pragma unroll
            for (int r = 0; r < 16; ++r) {
                float uv = su[r][i];
                accA[r] = fmaf(uv, wa, accA[r]);
                accB[r] = fmaf(uv, wb, accB[r]);
            }
        }
        float ba = b1[ja], bb2 = b1[jb];
        #pragma unroll
        for (int r = 0; r < 16; ++r) {
            st[r][t]       = gelu_tanh(accA[r] + ba);
            st[r][t + 256] = gelu_tanh(accB[r] + bb2);
        }
        __syncthreads();
        const float* w2p = w2 + (size_t)jj * 512 * 1024 + k0;
        #pragma unroll 2
        for (int i = 0; i < 512; ++i) {
            const float4 w = *(const float4*)(w2p + (size_t)i * 1024);
            #pragma unroll
            for (int r = 0; r < 16; ++r) {
                float tv = st[r][i];
                acc[r][0] = fmaf(tv, w.x, acc[r][0]);
                acc[r][1] = fmaf(tv, w.y, acc[r][1]);
                acc[r][2] = fmaf(tv, w.z, acc[r][2]);
                acc[r][3] = fmaf(tv, w.w, acc[r][3]);
            }
        }
    }

    const float4 bias = *(const float4*)(b2 + k0);
    #pragma unroll
    for (int r = 0; r < 16; ++r) {
        float ox = acc[r][0] + bias.x, oy = acc[r][1] + bias.y;
        float oz = acc[r][2] + bias.z, ow = acc[r][3] + bias.w;
        const int row = row0 + r;
        if (k0 < 512) {
            *(ushort4*)(v + (size_t)row * 512 + k0) = pack4(ox, oy, oz, ow);
        } else if (k0 < 768) {
            *(ushort4*)(uu + (size_t)row * 256 + (k0 - 512)) = pack4(ox, oy, oz, ow);
        } else {
            float4 o; o.x = ox; o.y = oy; o.z = oz; o.w = ow;
            *(float4*)(uskip + (size_t)row * 256 + (k0 - 768)) = o;
        }
    }
}

// ---------------------------------------------------------------- K2: means of uu (per batch)
__global__ void mean_over_lat_kernel(const u16* __restrict__ uu, float* __restrict__ Mlong) {
    int l = blockIdx.x, d = threadIdx.x;       // grid 256
    float s = 0.f;
    for (int i = 0; i < NLAT; ++i) s += b2f(uu[((size_t)i * NLON + l) * 256 + d]);
    Mlong[(size_t)l * 256 + d] = s * (1.0f / NLAT);
}
__global__ void mean_over_lon_kernel(const u16* __restrict__ uu, float* __restrict__ Mlat) {
    int i = blockIdx.x, d = threadIdx.x;       // grid 128
    const u16* p = uu + (size_t)i * NLON * 256 + d;
    float s = 0.f;
    for (int l = 0; l < NLON; ++l) s += b2f(p[(size_t)l * 256]);
    Mlat[(size_t)i * 256 + d] = s * (1.0f / NLON);
}

// ---------------------------------------------------------------- reduction helper
__device__ float block_sum256(float x, float* red) {
    #pragma unroll
    for (int o = 32; o > 0; o >>= 1) x += __shfl_down(x, o, 64);
    int wid = threadIdx.x >> 6, lane = threadIdx.x & 63;
    if (lane == 0) red[wid] = x;
    __syncthreads();
    float s = red[0] + red[1] + red[2] + red[3];
    __syncthreads();
    return s;
}

// ---------------------------------------------------------------- K3: pool MLP (per batch)
__global__ __launch_bounds__(256) void pool_mlp_kernel(
    const float* __restrict__ xin, const float* __restrict__ in_w,
    const float* __restrict__ ln_g, const float* __restrict__ ln_b,
    const float* __restrict__ fc1_w, const float* __restrict__ fc1_b,
    const float* __restrict__ fc2_w, const float* __restrict__ fc2_b,
    const float* __restrict__ lat, float* __restrict__ out)
{
    __shared__ float sx[256], sy[256], sg[256], red[4];
    int row = blockIdx.x, t = threadIdx.x;
    sx[t] = xin[(size_t)row * 256 + t];
    __syncthreads();
    float acc = 0.f;
    #pragma unroll 4
    for (int i = 0; i < 256; ++i) acc = fmaf(sx[i], in_w[i * 256 + t], acc);
    if (lat) acc *= lat_weight(lat, row, NLAT);
    float m = block_sum256(acc, red) * (1.f / 256.f);
    float var = block_sum256(acc * acc, red) * (1.f / 256.f) - m * m;
    float xn = (acc - m) * rsqrtf(var + 1e-5f) * ln_g[t] + ln_b[t];
    sy[t] = xn;
    __syncthreads();
    float h1 = fc1_b[t], h2 = fc1_b[t + 256];
    #pragma unroll 4
    for (int i = 0; i < 256; ++i) {
        float s = sy[i];
        h1 = fmaf(s, fc1_w[i * 512 + t], h1);
        h2 = fmaf(s, fc1_w[i * 512 + 256 + t], h2);
    }
    float g = h1 * gelu_tanh(h2);
    sg[t] = g;
    __syncthreads();
    float o = fc2_b[t];
    #pragma unroll 4
    for (int i = 0; i < 256; ++i) o = fmaf(sg[i], fc2_w[i * 256 + t], o);
    out[(size_t)row * 256 + t] = o;
}

// ---------------------------------------------------------------- K4: bessel mod (batch-independent)
__global__ void bessel_kernel(const float* __restrict__ coord, int n,
                              const float* __restrict__ freq, int nf,
                              const float* __restrict__ w, float* __restrict__ mod,
                              int periodic)
{
    int i = blockIdx.x, j = threadIdx.x;
    float d = fabsf(coord[j] - coord[i]);
    if (periodic) d = fminf(d, TWO_PI_F - d);
    float acc[8];
    #pragma unroll
    for (int h = 0; h < 8; ++h) acc[h] = 0.f;
    bool big = d > 1e-6f;
    float inv = big ? 1.f / d : 0.f;
    for (int k = 0; k < nf; ++k) {
        float f = freq[k];
        float basis = big ? sinf(f * d) * inv : f;
        #pragma unroll
        for (int h = 0; h < 8; ++h) acc[h] = fmaf(basis, w[k * 8 + h], acc[h]);
    }
    #pragma unroll
    for (int h = 0; h < 8; ++h) mod[((size_t)h * n + i) * n + j] = acc[h];
}

// ---------------------------------------------------------------- K5: q/k projections (per batch)
__global__ __launch_bounds__(256) void proj_kernel(const float* __restrict__ x,
                                                   const float* __restrict__ w,
                                                   float* __restrict__ c)
{
    __shared__ float sx[256];
    int row = blockIdx.x, t = threadIdx.x;
    sx[t] = x[(size_t)row * 256 + t];
    __syncthreads();
    for (int jj = 0; jj < 6; ++jj) {
        int j = t + jj * 256;
        float acc = 0.f;
        #pragma unroll 4
        for (int i = 0; i < 256; ++i) acc = fmaf(sx[i], w[(size_t)i * 1536 + j], acc);
        c[(size_t)row * 1536 + j] = acc;
    }
}

// ---------------------------------------------------------------- K6a: k_long^T (per batch), scale 2pi/256 folded
__global__ __launch_bounds__(256) void kmat_long_kernel(
    const float* __restrict__ q, const float* __restrict__ kp,
    const float* __restrict__ mod, float* __restrict__ KT)
{
    int blk = blockIdx.x;              // h*256 + j   (grid 2048)
    int j = blk & 255, h = blk >> 8;
    __shared__ float kr[192];
    int t = threadIdx.x;
    if (t < 192) kr[t] = kp[(size_t)j * 1536 + h * 192 + t];
    __syncthreads();
    const float* qp = q + (size_t)t * 1536 + h * 192;
    float acc = 0.f;
    #pragma unroll 4
    for (int c = 0; c < 192; ++c) acc = fmaf(qp[c], kr[c], acc);
    float mv = mod[((size_t)h * 256 + j) * 256 + t];  // mod symmetric in (i,j)
    float val = leaky(acc * mv) * (TWO_PI_F / 256.f);
    KT[((size_t)h * 256 + j) * 256 + t] = val;        // KT[h][m=j][l=t]
}

// ---------------------------------------------------------------- K6b: k_lat (per batch), wlat[j]*pi/128 folded
__global__ __launch_bounds__(128) void kmat_lat_kernel(
    const float* __restrict__ q, const float* __restrict__ kp,
    const float* __restrict__ mod, const float* __restrict__ lat, float* __restrict__ K)
{
    int blk = blockIdx.x;              // h*128 + i   (grid 1024)
    int i = blk & 127, h = blk >> 7;
    __shared__ float qr[192];
    int t = threadIdx.x;
    for (int c = t; c < 192; c += 128) qr[c] = q[(size_t)i * 1536 + h * 192 + c];
    __syncthreads();
    const float* kpp = kp + (size_t)t * 1536 + h * 192;
    float acc = 0.f;
    #pragma unroll 4
    for (int c = 0; c < 192; ++c) acc = fmaf(kpp[c], qr[c], acc);
    float mv = mod[((size_t)h * 128 + i) * 128 + t];
    float wl = lat_weight(lat, t, NLAT);
    float val = leaky(acc * mv) * wl * (PI_F / 128.f);
    K[((size_t)h * 128 + i) * 128 + t] = val;
}

// ---------------------------------------------------------------- K7: einsum1 (per batch)
// tmp1[h,i,m,c] = sum_j Klat[h,i,j] * v[j,m,h*64+c]
__global__ __launch_bounds__(256) void einsum1_kernel(
    const float* __restrict__ Klat, const u16* __restrict__ v, u16* __restrict__ tmp1)
{
    int blk = blockIdx.x;              // h*16 + ig   (grid 128)
    int ig = blk & 15, h = blk >> 4;
    __shared__ float sk[8][128];
    int t = threadIdx.x;
    for (int x = t; x < 1024; x += 256) {
        int r = x >> 7, j = x & 127;
        sk[r][j] = Klat[((size_t)h * 128 + ig * 8 + r) * 128 + j];
    }
    __syncthreads();
    int c = t & 63, mg = t >> 6;
    const u16* vb = v + h * 64 + c;
    for (int mi = 0; mi < 64; ++mi) {
        int m = mi * 4 + mg;
        float acc[8];
        #pragma unroll
        for (int r = 0; r < 8; ++r) acc[r] = 0.f;
        const u16* vp = vb + (size_t)m * 512;
        #pragma unroll 2
        for (int j = 0; j < 128; ++j) {
            float vv = b2f(vp[(size_t)j * NLON * 512]);
            #pragma unroll
            for (int r = 0; r < 8; ++r) acc[r] = fmaf(sk[r][j], vv, acc[r]);
        }
        #pragma unroll
        for (int r = 0; r < 8; ++r)
            tmp1[(((size_t)h * 128 + ig * 8 + r) * 256 + m) * 64 + c] = f2b(acc[r]);
    }
}

// ---------------------------------------------------------------- K8: einsum2 + transpose + GN stats (per batch)
// A[i,l,h*64+c] = sum_m KlongT[h,m,l] * tmp1[h,i,m,c]
__global__ __launch_bounds__(256) void einsum2_kernel(
    const u16* __restrict__ tmp1, const float* __restrict__ KlongT,
    u16* __restrict__ A, float* __restrict__ gnstat)
{
    int blk = blockIdx.x;              // h*128 + i   (grid 1024)
    int i = blk & 127, h = blk >> 7;
    __shared__ __align__(16) float st1[16384];  // [m][c] fp32
    int t = threadIdx.x;
    const u16* src = tmp1 + (size_t)blk * 16384;
    for (int x = t; x < 16384; x += 256) st1[x] = b2f(src[x]);
    __syncthreads();
    int cg = t & 15, lg = t >> 4;
    const float* kT = KlongT + (size_t)h * 65536;
    float lsum = 0.f, lsq = 0.f;
    for (int lo = 0; lo < 4; ++lo) {
        int l0 = lo * 64 + lg * 4;
        float acc[4][4];
        #pragma unroll
        for (int a = 0; a < 4; ++a)
            #pragma unroll
            for (int bb2 = 0; bb2 < 4; ++bb2) acc[a][bb2] = 0.f;
        #pragma unroll 4
        for (int m = 0; m < 256; ++m) {
            float4 kl = *(const float4*)(kT + (size_t)m * 256 + l0);
            float4 tv = *(const float4*)(st1 + m * 64 + cg * 4);
            acc[0][0] = fmaf(kl.x, tv.x, acc[0][0]); acc[0][1] = fmaf(kl.x, tv.y, acc[0][1]);
            acc[0][2] = fmaf(kl.x, tv.z, acc[0][2]); acc[0][3] = fmaf(kl.x, tv.w, acc[0][3]);
            acc[1][0] = fmaf(kl.y, tv.x, acc[1][0]); acc[1][1] = fmaf(kl.y, tv.y, acc[1][1]);
            acc[1][2] = fmaf(kl.y, tv.z, acc[1][2]); acc[1][3] = fmaf(kl.y, tv.w, acc[1][3]);
            acc[2][0] = fmaf(kl.z, tv.x, acc[2][0]); acc[2][1] = fmaf(kl.z, tv.y, acc[2][1]);
            acc[2][2] = fmaf(kl.z, tv.z, acc[2][2]); acc[2][3] = fmaf(kl.z, tv.w, acc[2][3]);
            acc[3][0] = fmaf(kl.w, tv.x, acc[3][0]); acc[3][1] = fmaf(kl.w, tv.y, acc[3][1]);
            acc[3][2] = fmaf(kl.w, tv.z, acc[3][2]); acc[3][3] = fmaf(kl.w, tv.w, acc[3][3]);
        }
        #pragma unroll
        for (int li = 0; li < 4; ++li) {
            int l = l0 + li;
            *(ushort4*)(A + ((size_t)i * 256 + l) * 512 + h * 64 + cg * 4) =
                pack4(acc[li][0], acc[li][1], acc[li][2], acc[li][3]);
            lsum += acc[li][0] + acc[li][1] + acc[li][2] + acc[li][3];
            lsq  += acc[li][0] * acc[li][0] + acc[li][1] * acc[li][1]
                  + acc[li][2] * acc[li][2] + acc[li][3] * acc[li][3];
        }
    }
    __syncthreads();   // st1 reads done; reuse for reduction
    #pragma unroll
    for (int o = 32; o > 0; o >>= 1) {
        lsum += __shfl_down(lsum, o, 64);
        lsq  += __shfl_down(lsq, o, 64);
    }
    int wid = t >> 6, lane = t & 63;
    if (lane == 0) { st1[wid] = lsum; st1[8 + wid] = lsq; }
    __syncthreads();
    if (t == 0) {
        atomicAdd(&gnstat[h * 2],     st1[0] + st1[1] + st1[2] + st1[3]);
        atomicAdd(&gnstat[h * 2 + 1], st1[8] + st1[9] + st1[10] + st1[11]);
    }
}

// ---------------------------------------------------------------- K9: GN apply + merge GEMM + skip (per batch)
__global__ __launch_bounds__(128) void gn_merge_kernel(
    const u16* __restrict__ A, const float* __restrict__ gnstat,
    const float* __restrict__ gn_g, const float* __restrict__ gn_b,
    const float* __restrict__ mw, const float* __restrict__ uskip, float* __restrict__ D)
{
    __shared__ float sx[16][516];
    __shared__ float sm[8], siv[8];
    int t = threadIdx.x;
    int row0 = blockIdx.x * 16;        // grid 2048 -> 32768 rows
    if (t < 8) {
        const float Ninv = 1.f / 2097152.f;   // 128*256*64
        float s1 = gnstat[t * 2], s2 = gnstat[t * 2 + 1];
        float m = s1 * Ninv;
        float var = s2 * Ninv - m * m;
        sm[t] = m; siv[t] = rsqrtf(var + 1e-5f);
    }
    __syncthreads();
    for (int r = 0; r < 16; ++r)
        for (int d = t; d < 512; d += 128) {
            float x = b2f(A[(size_t)(row0 + r) * 512 + d]);
            int h = d >> 6;
            sx[r][d] = (x - sm[h]) * siv[h] * gn_g[d] + gn_b[d];
        }
    __syncthreads();
    float a0[16], a1[16];
    #pragma unroll
    for (int r = 0; r < 16; ++r) { a0[r] = 0.f; a1[r] = 0.f; }
    #pragma unroll 2
    for (int i = 0; i < 512; ++i) {
        float w0 = mw[i * 256 + t], w1 = mw[i * 256 + t + 128];
        #pragma unroll
        for (int r = 0; r < 16; ++r) {
            float xv = sx[r][i];
            a0[r] = fmaf(xv, w0, a0[r]);
            a1[r] = fmaf(xv, w1, a1[r]);
        }
    }
    #pragma unroll
    for (int r = 0; r < 16; ++r) {
        size_t base = (size_t)(row0 + r) * 256;
        D[base + t]       = a0[r] + uskip[base + t];
        D[base + t + 128] = a1[r] + uskip[base + t + 128];
    }
}

// ---------------------------------------------------------------- K10: final GEMM (per batch)
__global__ __launch_bounds__(128) void out_gemm_kernel(
    const float* __restrict__ D, const float* __restrict__ ow, float* __restrict__ out)
{
    __shared__ float sx[16][260];
    int t = threadIdx.x;
    int row0 = blockIdx.x * 16;        // grid 2048
    for (int r = 0; r < 16; ++r)
        for (int d = t; d < 256; d += 128) sx[r][d] = D[(size_t)(row0 + r) * 256 + d];
    __syncthreads();
    float a0[16], a1[16];
    #pragma unroll
    for (int r = 0; r < 16; ++r) { a0[r] = 0.f; a1[r] = 0.f; }
    #pragma unroll 2
    for (int i = 0; i < 256; ++i) {
        float w0 = ow[i * 256 + t], w1 = ow[i * 256 + t + 128];
        #pragma unroll
        for (int r = 0; r < 16; ++r) {
            float xv = sx[r][i];
            a0[r] = fmaf(xv, w0, a0[r]);
            a1[r] = fmaf(xv, w1, a1[r]);
        }
    }
    #pragma unroll
    for (int r = 0; r < 16; ++r) {
        size_t base = (size_t)(row0 + r) * 256;
        out[base + t]       = a0[r];
        out[base + t + 128] = a1[r];
    }
}

__global__ void zero_kernel(float* __restrict__ p, int n) {
    int i = blockIdx.x * blockDim.x + threadIdx.x;
    if (i < n) p[i] = 0.f;
}

// ================================================================ launch
// Workspace (bytes):
//   region0 (vA):   33,554,432  v bf16 (16.8M) -> A bf16 (16.8M)
//   region1:        33,554,432  uu bf16 (8.4M) -> tmp1 bf16 (16.8M) -> D fp32 (8.4M)
//   mods+small:     10,748,032
//   TOTAL:          77,856,896  (74.3 MB). uskip lives in d_out halves.
extern "C" void kernel_launch(void* const* d_in, const int* in_sizes, int n_in,
                              void* d_out, int out_size, void* d_ws, size_t ws_size,
                              hipStream_t stream) {
    if (ws_size < 77856896ULL) return;   // diagnostic guard: clean numeric fail, not a fault

    const float* u        = (const float*)d_in[0];
    const float* lat      = (const float*)d_in[1];
    const float* lon      = (const float*)d_in[2];
    const float* cm_w1    = (const float*)d_in[3];
    const float* cm_b1    = (const float*)d_in[4];
    const float* cm_w2    = (const float*)d_in[5];
    const float* cm_b2    = (const float*)d_in[6];
    const float* long_in_w  = (const float*)d_in[7];
    const float* long_ln_g  = (const float*)d_in[8];
    const float* long_ln_b  = (const float*)d_in[9];
    const float* long_fc1_w = (const float*)d_in[10];
    const float* long_fc1_b = (const float*)d_in[11];
    const float* long_fc2_w = (const float*)d_in[12];
    const float* long_fc2_b = (const float*)d_in[13];
    const float* lat_in_w   = (const float*)d_in[14];
    const float* lat_ln_g   = (const float*)d_in[15];
    const float* lat_ln_b   = (const float*)d_in[16];
    const float* lat_fc1_w  = (const float*)d_in[17];
    const float* lat_fc1_b  = (const float*)d_in[18];
    const float* lat_fc2_w  = (const float*)d_in[19];
    const float* lat_fc2_b  = (const float*)d_in[20];
    const float* klong_q_w  = (const float*)d_in[21];
    const float* klong_k_w  = (const float*)d_in[22];
    const float* klat_q_w   = (const float*)d_in[23];
    const float* klat_k_w   = (const float*)d_in[24];
    const float* pe_long_freq = (const float*)d_in[25];
    const float* pe_long_w    = (const float*)d_in[26];
    const float* pe_lat_freq  = (const float*)d_in[27];
    const float* pe_lat_w     = (const float*)d_in[28];
    const float* gn_g    = (const float*)d_in[29];
    const float* gn_b    = (const float*)d_in[30];
    const float* merge_w = (const float*)d_in[31];
    const float* out_w   = (const float*)d_in[32];
    float* out = (float*)d_out;

    char* base = (char*)d_ws;
    u16*  vA   = (u16*)base;                          // v then A (bf16, 16.8M elems)
    char* reg1 = base + 33554432;
    u16*  uu   = (u16*)reg1;                          // 8.4M bf16
    u16*  tmp1 = (u16*)reg1;                          // 16.8M bf16 (after uu dead)
    float* D   = (float*)reg1;                        // 8.4M fp32 (after tmp1 dead)
    float* modlong = (float*)(base + 67108864);       // 524,288
    float* modlat  = modlong + 524288;                // 131,072
    float* Mlong   = modlat + 131072;                 // 65,536
    float* Mlat    = Mlong + 65536;                   // 32,768
    float* ulong   = Mlat + 32768;                    // 65,536
    float* ulat    = ulong + 65536;                   // 32,768
    float* qlong   = ulat + 32768;                    // 393,216
    float* klongp  = qlong + 393216;                  // 393,216
    float* qlat    = klongp + 393216;                 // 196,608
    float* klatp   = qlat + 196608;                   // 196,608
    float* KlongT  = klatp + 196608;                  // 524,288
    float* Klat    = KlongT + 524288;                 // 131,072
    float* gnstat  = Klat + 131072;                   // 32

    zero_kernel<<<1, 32, 0, stream>>>(gnstat, 32);
    bessel_kernel<<<256, 256, 0, stream>>>(lon, 256, pe_long_freq, 64, pe_long_w, modlong, 1);
    bessel_kernel<<<128, 128, 0, stream>>>(lat, 128, pe_lat_freq, 32, pe_lat_w, modlat, 0);

    for (int b = 0; b < 2; ++b) {
        const float* u_b  = u + (size_t)b * 32768 * 256;
        float* uskip_b    = out + (size_t)b * 8388608;
        float* gnstat_b   = gnstat + b * 16;

        cm_mlp_kernel<<<2048, 256, 0, stream>>>(u_b, cm_w1, cm_b1, cm_w2, cm_b2,
                                                vA, uu, uskip_b);
        mean_over_lat_kernel<<<256, 256, 0, stream>>>(uu, Mlong);
        mean_over_lon_kernel<<<128, 256, 0, stream>>>(uu, Mlat);
        pool_mlp_kernel<<<256, 256, 0, stream>>>(Mlong, long_in_w, long_ln_g, long_ln_b,
                                                 long_fc1_w, long_fc1_b, long_fc2_w, long_fc2_b,
                                                 nullptr, ulong);
        pool_mlp_kernel<<<128, 256, 0, stream>>>(Mlat, lat_in_w, lat_ln_g, lat_ln_b,
                                                 lat_fc1_w, lat_fc1_b, lat_fc2_w, lat_fc2_b,
                                                 lat, ulat);
        proj_kernel<<<256, 256, 0, stream>>>(ulong, klong_q_w, qlong);
        proj_kernel<<<256, 256, 0, stream>>>(ulong, klong_k_w, klongp);
        proj_kernel<<<128, 256, 0, stream>>>(ulat, klat_q_w, qlat);
        proj_kernel<<<128, 256, 0, stream>>>(ulat, klat_k_w, klatp);
        kmat_long_kernel<<<2048, 256, 0, stream>>>(qlong, klongp, modlong, KlongT);
        kmat_lat_kernel<<<1024, 128, 0, stream>>>(qlat, klatp, modlat, lat, Klat);
        einsum1_kernel<<<128, 256, 0, stream>>>(Klat, vA, tmp1);        // tmp1 overwrites uu (dead)
        einsum2_kernel<<<1024, 256, 0, stream>>>(tmp1, KlongT, vA, gnstat_b);  // A overwrites v (dead)
        gn_merge_kernel<<<2048, 128, 0, stream>>>(vA, gnstat_b, gn_g, gn_b, merge_w,
                                                  uskip_b, D);          // D overwrites tmp1 (dead)
        out_gemm_kernel<<<2048, 128, 0, stream>>>(D, out_w, out + (size_t)b * 8388608);
    }
}

// Round 4
// 5210.664 us; speedup vs baseline: 1.7825x; 1.7825x over previous
//
#include <hip/hip_runtime.h>
#include <math.h>
#include <stdint.h>

#define NLAT 128
#define NLON 256
#define PI_F 3.14159265358979323846f
#define TWO_PI_F 6.28318530717958647692f

typedef unsigned short u16;
typedef __attribute__((ext_vector_type(8))) short bf16x8;
typedef __attribute__((ext_vector_type(4))) float f32x4;

__device__ __forceinline__ u16 f2b(float f) {          // fp32 -> bf16 RNE
    union { float f; uint32_t u; } v; v.f = f;
    uint32_t r = v.u + 0x7fffu + ((v.u >> 16) & 1u);
    return (u16)(r >> 16);
}
__device__ __forceinline__ float b2f(u16 u) {          // bf16 -> fp32 exact
    union { uint32_t u; float f; } v; v.u = ((uint32_t)u) << 16;
    return v.f;
}
__device__ __forceinline__ ushort4 pack4(float a, float b, float c, float d) {
    ushort4 r; r.x = f2b(a); r.y = f2b(b); r.z = f2b(c); r.w = f2b(d); return r;
}

__device__ __forceinline__ float gelu_tanh(float x) {
    float x3 = x * x * x;
    return 0.5f * x * (1.0f + tanhf(0.7978845608028654f * (x + 0.044715f * x3)));
}
__device__ __forceinline__ float leaky(float x) { return x >= 0.0f ? x : 0.2f * x; }

__device__ __forceinline__ float lat_weight(const float* __restrict__ lat, int i, int n) {
    float w = cosf(lat[i]);
    if ((i == 0 || i == n - 1) && w < 0.001f) {
        float dlat = lat[1] - lat[0];
        float s = sinf(dlat * 0.25f);
        w = s * s / sinf(dlat * 0.5f);  // POLAR_EPS = 1
    }
    return w;
}

// ---------------------------------------------------------------- W conversions (per batch; alias pool)
__global__ void conv_w1t_kernel(const float* __restrict__ w1, u16* __restrict__ w1t) {
    // w1 [256][1536] fp32 -> w1t [1536][256] bf16
    int idx = blockIdx.x * 256 + threadIdx.x;       // grid 1536
    int j = idx >> 8, i = idx & 255;
    w1t[idx] = f2b(w1[(size_t)i * 1536 + j]);
}
__global__ void conv_w2t_kernel(const float* __restrict__ w2, u16* __restrict__ w2t) {
    // w2 [1536][1024] fp32 -> w2t [1024][1536] bf16
    int k = blockIdx.x / 6, s = blockIdx.x % 6;     // grid 6144
    int i = s * 256 + threadIdx.x;
    w2t[(size_t)k * 1536 + i] = f2b(w2[(size_t)i * 1024 + k]);
}

// ---------------------------------------------------------------- K1: cm MLP via MFMA (per batch)
// 16 rows/block. GEMM1: hidden=gelu(u@W1+b1) in 3 chunks of 512 (LDS bf16);
// GEMM2 accumulates t@W2 into 16x1024 per block. Outputs v|uu bf16, uskip fp32.
// A-frag: A[m=lane&15][k=(lane>>4)*8+j]; B-frag: B[k=(lane>>4)*8+j][n=lane&15];
// D: row=(lane>>4)*4+r, col=lane&15  (guide-verified layouts).
__global__ __launch_bounds__(256, 2) void cm_mlp_mfma_kernel(
    const float* __restrict__ u, const u16* __restrict__ w1t, const float* __restrict__ b1,
    const u16* __restrict__ w2t, const float* __restrict__ b2,
    u16* __restrict__ v, u16* __restrict__ uu, float* __restrict__ uskip)
{
    __shared__ __align__(16) u16 sA[16][264];   // +8 pad: 2-way bank alias (free)
    __shared__ __align__(16) u16 sH[16][520];
    const int t = threadIdx.x;
    const int lane = t & 63, w = t >> 6;
    const int ln = lane & 15, q = lane >> 4;
    const int row0 = blockIdx.x * 16;

    // stage u fp32 -> bf16 (coalesced float4)
    for (int x = t; x < 1024; x += 256) {
        int r = x >> 6, c0 = (x & 63) * 4;
        float4 xx = *(const float4*)(u + (size_t)(row0 + r) * 256 + c0);
        sA[r][c0 + 0] = f2b(xx.x); sA[r][c0 + 1] = f2b(xx.y);
        sA[r][c0 + 2] = f2b(xx.z); sA[r][c0 + 3] = f2b(xx.w);
    }

    f32x4 c2[16];
    #pragma unroll
    for (int i = 0; i < 16; ++i) c2[i] = (f32x4){0.f, 0.f, 0.f, 0.f};

    for (int jj = 0; jj < 3; ++jj) {
        __syncthreads();   // jj=0: sA ready; else: sH of prev chunk fully consumed
        // ---- GEMM1: this wave covers hidden cols [w*128, w*128+128) of chunk jj
        f32x4 c1[8];
        #pragma unroll
        for (int i = 0; i < 8; ++i) c1[i] = (f32x4){0.f, 0.f, 0.f, 0.f};
        {
            const u16* w1p = w1t + (size_t)(jj * 512 + w * 128 + ln) * 256 + q * 8;
            #pragma unroll
            for (int k0 = 0; k0 < 256; k0 += 32) {
                bf16x8 a = *(const bf16x8*)&sA[ln][k0 + q * 8];
                #pragma unroll
                for (int nt = 0; nt < 8; ++nt) {
                    bf16x8 b = *(const bf16x8*)(w1p + (size_t)nt * 16 * 256 + k0);
                    c1[nt] = __builtin_amdgcn_mfma_f32_16x16x32_bf16(a, b, c1[nt], 0, 0, 0);
                }
            }
        }
        // bias + gelu -> sH (each wave writes its own 128-col slice; no race)
        #pragma unroll
        for (int nt = 0; nt < 8; ++nt) {
            int col = w * 128 + nt * 16 + ln;
            float bias = b1[jj * 512 + col];
            #pragma unroll
            for (int r = 0; r < 4; ++r)
                sH[q * 4 + r][col] = f2b(gelu_tanh(c1[nt][r] + bias));
        }
        __syncthreads();
        // ---- GEMM2: K-chunk jj, wave covers out cols [w*256, w*256+256)
        const u16* w2p = w2t + (size_t)(w * 256 + ln) * 1536 + jj * 512 + q * 8;
        #pragma unroll 2
        for (int k0 = 0; k0 < 512; k0 += 32) {
            bf16x8 a = *(const bf16x8*)&sH[ln][k0 + q * 8];
            #pragma unroll
            for (int nt = 0; nt < 16; ++nt) {
                bf16x8 b = *(const bf16x8*)(w2p + (size_t)nt * 16 * 1536 + k0);
                c2[nt] = __builtin_amdgcn_mfma_f32_16x16x32_bf16(a, b, c2[nt], 0, 0, 0);
            }
        }
    }

    // epilogue: scatter stores (quad-contiguous 32B bf16 segments)
    #pragma unroll
    for (int nt = 0; nt < 16; ++nt) {
        int col = w * 256 + nt * 16 + ln;
        float bias = b2[col];
        #pragma unroll
        for (int r = 0; r < 4; ++r) {
            int row = row0 + q * 4 + r;
            float val = c2[nt][r] + bias;
            if (col < 512)      v[(size_t)row * 512 + col] = f2b(val);
            else if (col < 768) uu[(size_t)row * 256 + (col - 512)] = f2b(val);
            else                uskip[(size_t)row * 256 + (col - 768)] = val;
        }
    }
}

// ---------------------------------------------------------------- K2: means of uu (per batch)
__global__ void mean_over_lat_kernel(const u16* __restrict__ uu, float* __restrict__ Mlong) {
    int l = blockIdx.x, d = threadIdx.x;       // grid 256
    float s = 0.f;
    for (int i = 0; i < NLAT; ++i) s += b2f(uu[((size_t)i * NLON + l) * 256 + d]);
    Mlong[(size_t)l * 256 + d] = s * (1.0f / NLAT);
}
__global__ void mean_over_lon_kernel(const u16* __restrict__ uu, float* __restrict__ Mlat) {
    int i = blockIdx.x, d = threadIdx.x;       // grid 128
    const u16* p = uu + (size_t)i * NLON * 256 + d;
    float s = 0.f;
    for (int l = 0; l < NLON; ++l) s += b2f(p[(size_t)l * 256]);
    Mlat[(size_t)i * 256 + d] = s * (1.0f / NLON);
}

// ---------------------------------------------------------------- reduction helper
__device__ float block_sum256(float x, float* red) {
    #pragma unroll
    for (int o = 32; o > 0; o >>= 1) x += __shfl_down(x, o, 64);
    int wid = threadIdx.x >> 6, lane = threadIdx.x & 63;
    if (lane == 0) red[wid] = x;
    __syncthreads();
    float s = red[0] + red[1] + red[2] + red[3];
    __syncthreads();
    return s;
}

// ---------------------------------------------------------------- K3: pool MLP (per batch)
__global__ __launch_bounds__(256) void pool_mlp_kernel(
    const float* __restrict__ xin, const float* __restrict__ in_w,
    const float* __restrict__ ln_g, const float* __restrict__ ln_b,
    const float* __restrict__ fc1_w, const float* __restrict__ fc1_b,
    const float* __restrict__ fc2_w, const float* __restrict__ fc2_b,
    const float* __restrict__ lat, float* __restrict__ out)
{
    __shared__ float sx[256], sy[256], sg[256], red[4];
    int row = blockIdx.x, t = threadIdx.x;
    sx[t] = xin[(size_t)row * 256 + t];
    __syncthreads();
    float acc = 0.f;
    #pragma unroll 4
    for (int i = 0; i < 256; ++i) acc = fmaf(sx[i], in_w[i * 256 + t], acc);
    if (lat) acc *= lat_weight(lat, row, NLAT);
    float m = block_sum256(acc, red) * (1.f / 256.f);
    float var = block_sum256(acc * acc, red) * (1.f / 256.f) - m * m;
    float xn = (acc - m) * rsqrtf(var + 1e-5f) * ln_g[t] + ln_b[t];
    sy[t] = xn;
    __syncthreads();
    float h1 = fc1_b[t], h2 = fc1_b[t + 256];
    #pragma unroll 4
    for (int i = 0; i < 256; ++i) {
        float s = sy[i];
        h1 = fmaf(s, fc1_w[i * 512 + t], h1);
        h2 = fmaf(s, fc1_w[i * 512 + 256 + t], h2);
    }
    float g = h1 * gelu_tanh(h2);
    sg[t] = g;
    __syncthreads();
    float o = fc2_b[t];
    #pragma unroll 4
    for (int i = 0; i < 256; ++i) o = fmaf(sg[i], fc2_w[i * 256 + t], o);
    out[(size_t)row * 256 + t] = o;
}

// ---------------------------------------------------------------- K4: bessel mod (batch-independent)
__global__ void bessel_kernel(const float* __restrict__ coord, int n,
                              const float* __restrict__ freq, int nf,
                              const float* __restrict__ w, float* __restrict__ mod,
                              int periodic)
{
    int i = blockIdx.x, j = threadIdx.x;
    float d = fabsf(coord[j] - coord[i]);
    if (periodic) d = fminf(d, TWO_PI_F - d);
    float acc[8];
    #pragma unroll
    for (int h = 0; h < 8; ++h) acc[h] = 0.f;
    bool big = d > 1e-6f;
    float inv = big ? 1.f / d : 0.f;
    for (int k = 0; k < nf; ++k) {
        float f = freq[k];
        float basis = big ? sinf(f * d) * inv : f;
        #pragma unroll
        for (int h = 0; h < 8; ++h) acc[h] = fmaf(basis, w[k * 8 + h], acc[h]);
    }
    #pragma unroll
    for (int h = 0; h < 8; ++h) mod[((size_t)h * n + i) * n + j] = acc[h];
}

// ---------------------------------------------------------------- K5: q/k projections (per batch)
__global__ __launch_bounds__(256) void proj_kernel(const float* __restrict__ x,
                                                   const float* __restrict__ w,
                                                   float* __restrict__ c)
{
    __shared__ float sx[256];
    int row = blockIdx.x, t = threadIdx.x;
    sx[t] = x[(size_t)row * 256 + t];
    __syncthreads();
    for (int jj = 0; jj < 6; ++jj) {
        int j = t + jj * 256;
        float acc = 0.f;
        #pragma unroll 4
        for (int i = 0; i < 256; ++i) acc = fmaf(sx[i], w[(size_t)i * 1536 + j], acc);
        c[(size_t)row * 1536 + j] = acc;
    }
}

// ---------------------------------------------------------------- K6a: k_long^T (per batch), 2pi/256 folded
__global__ __launch_bounds__(256) void kmat_long_kernel(
    const float* __restrict__ q, const float* __restrict__ kp,
    const float* __restrict__ mod, float* __restrict__ KT)
{
    int blk = blockIdx.x;              // h*256 + j   (grid 2048)
    int j = blk & 255, h = blk >> 8;
    __shared__ float kr[192];
    int t = threadIdx.x;
    if (t < 192) kr[t] = kp[(size_t)j * 1536 + h * 192 + t];
    __syncthreads();
    const float* qp = q + (size_t)t * 1536 + h * 192;
    float acc = 0.f;
    #pragma unroll 4
    for (int c = 0; c < 192; ++c) acc = fmaf(qp[c], kr[c], acc);
    float mv = mod[((size_t)h * 256 + j) * 256 + t];  // mod symmetric in (i,j)
    float val = leaky(acc * mv) * (TWO_PI_F / 256.f);
    KT[((size_t)h * 256 + j) * 256 + t] = val;        // KT[h][m=j][l=t]
}

// ---------------------------------------------------------------- K6b: k_lat (per batch), wlat[j]*pi/128 folded
__global__ __launch_bounds__(128) void kmat_lat_kernel(
    const float* __restrict__ q, const float* __restrict__ kp,
    const float* __restrict__ mod, const float* __restrict__ lat, float* __restrict__ K)
{
    int blk = blockIdx.x;              // h*128 + i   (grid 1024)
    int i = blk & 127, h = blk >> 7;
    __shared__ float qr[192];
    int t = threadIdx.x;
    for (int c = t; c < 192; c += 128) qr[c] = q[(size_t)i * 1536 + h * 192 + c];
    __syncthreads();
    const float* kpp = kp + (size_t)t * 1536 + h * 192;
    float acc = 0.f;
    #pragma unroll 4
    for (int c = 0; c < 192; ++c) acc = fmaf(kpp[c], qr[c], acc);
    float mv = mod[((size_t)h * 128 + i) * 128 + t];
    float wl = lat_weight(lat, t, NLAT);
    float val = leaky(acc * mv) * wl * (PI_F / 128.f);
    K[((size_t)h * 128 + i) * 128 + t] = val;
}

// ---------------------------------------------------------------- K7: einsum1 (per batch)
// tmp1[h,i,m,c] = sum_j Klat[h,i,j] * v[j,m,h*64+c]
// block: (h, ig of 16 i's, mc of 32 m's) -> grid 512; packed u32 bf16 loads.
__global__ __launch_bounds__(256) void einsum1_kernel(
    const float* __restrict__ Klat, const u16* __restrict__ v, u16* __restrict__ tmp1)
{
    int blk = blockIdx.x;
    int mc = blk & 7, ig = (blk >> 3) & 7, h = blk >> 6;
    __shared__ float sk[16][128];
    int t = threadIdx.x;
    for (int x = t; x < 2048; x += 256) {
        int r = x >> 7, j = x & 127;
        sk[r][j] = Klat[((size_t)h * 128 + ig * 16 + r) * 128 + j];
    }
    __syncthreads();
    int c2g = t & 31, mg = t >> 5;              // c = 2*c2g, 2*c2g+1; 8 m-subgroups
    const u16* vb = v + h * 64 + c2g * 2;
    for (int mi = 0; mi < 4; ++mi) {
        int m = mc * 32 + mi * 8 + mg;
        float acc0[16], acc1[16];
        #pragma unroll
        for (int r = 0; r < 16; ++r) { acc0[r] = 0.f; acc1[r] = 0.f; }
        const u16* vp = vb + (size_t)m * 512;
        #pragma unroll 2
        for (int j = 0; j < 128; ++j) {
            uint32_t pk = *(const uint32_t*)(vp + (size_t)j * (NLON * 512));
            float v0 = b2f((u16)(pk & 0xffffu));
            float v1 = b2f((u16)(pk >> 16));
            #pragma unroll
            for (int r = 0; r < 16; ++r) {
                acc0[r] = fmaf(sk[r][j], v0, acc0[r]);
                acc1[r] = fmaf(sk[r][j], v1, acc1[r]);
            }
        }
        #pragma unroll
        for (int r = 0; r < 16; ++r) {
            size_t off = (((size_t)h * 128 + ig * 16 + r) * 256 + m) * 64 + c2g * 2;
            uint32_t pk2 = (uint32_t)f2b(acc0[r]) | ((uint32_t)f2b(acc1[r]) << 16);
            *(uint32_t*)(tmp1 + off) = pk2;
        }
    }
}

// ---------------------------------------------------------------- K8: einsum2 + transpose + GN stats (per batch)
__global__ __launch_bounds__(256) void einsum2_kernel(
    const u16* __restrict__ tmp1, const float* __restrict__ KlongT,
    u16* __restrict__ A, float* __restrict__ gnstat)
{
    int blk = blockIdx.x;              // h*128 + i   (grid 1024)
    int i = blk & 127, h = blk >> 7;
    __shared__ __align__(16) float st1[16384];  // [m][c] fp32
    int t = threadIdx.x;
    const u16* src = tmp1 + (size_t)blk * 16384;
    for (int x = t; x < 16384; x += 256) st1[x] = b2f(src[x]);
    __syncthreads();
    int cg = t & 15, lg = t >> 4;
    const float* kT = KlongT + (size_t)h * 65536;
    float lsum = 0.f, lsq = 0.f;
    for (int lo = 0; lo < 4; ++lo) {
        int l0 = lo * 64 + lg * 4;
        float acc[4][4];
        #pragma unroll
        for (int a = 0; a < 4; ++a)
            #pragma unroll
            for (int bb2 = 0; bb2 < 4; ++bb2) acc[a][bb2] = 0.f;
        #pragma unroll 4
        for (int m = 0; m < 256; ++m) {
            float4 kl = *(const float4*)(kT + (size_t)m * 256 + l0);
            float4 tv = *(const float4*)(st1 + m * 64 + cg * 4);
            acc[0][0] = fmaf(kl.x, tv.x, acc[0][0]); acc[0][1] = fmaf(kl.x, tv.y, acc[0][1]);
            acc[0][2] = fmaf(kl.x, tv.z, acc[0][2]); acc[0][3] = fmaf(kl.x, tv.w, acc[0][3]);
            acc[1][0] = fmaf(kl.y, tv.x, acc[1][0]); acc[1][1] = fmaf(kl.y, tv.y, acc[1][1]);
            acc[1][2] = fmaf(kl.y, tv.z, acc[1][2]); acc[1][3] = fmaf(kl.y, tv.w, acc[1][3]);
            acc[2][0] = fmaf(kl.z, tv.x, acc[2][0]); acc[2][1] = fmaf(kl.z, tv.y, acc[2][1]);
            acc[2][2] = fmaf(kl.z, tv.z, acc[2][2]); acc[2][3] = fmaf(kl.z, tv.w, acc[2][3]);
            acc[3][0] = fmaf(kl.w, tv.x, acc[3][0]); acc[3][1] = fmaf(kl.w, tv.y, acc[3][1]);
            acc[3][2] = fmaf(kl.w, tv.z, acc[3][2]); acc[3][3] = fmaf(kl.w, tv.w, acc[3][3]);
        }
        #pragma unroll
        for (int li = 0; li < 4; ++li) {
            int l = l0 + li;
            *(ushort4*)(A + ((size_t)i * 256 + l) * 512 + h * 64 + cg * 4) =
                pack4(acc[li][0], acc[li][1], acc[li][2], acc[li][3]);
            lsum += acc[li][0] + acc[li][1] + acc[li][2] + acc[li][3];
            lsq  += acc[li][0] * acc[li][0] + acc[li][1] * acc[li][1]
                  + acc[li][2] * acc[li][2] + acc[li][3] * acc[li][3];
        }
    }
    __syncthreads();   // st1 reads done; reuse for reduction
    #pragma unroll
    for (int o = 32; o > 0; o >>= 1) {
        lsum += __shfl_down(lsum, o, 64);
        lsq  += __shfl_down(lsq, o, 64);
    }
    int wid = t >> 6, lane = t & 63;
    if (lane == 0) { st1[wid] = lsum; st1[8 + wid] = lsq; }
    __syncthreads();
    if (t == 0) {
        atomicAdd(&gnstat[h * 2],     st1[0] + st1[1] + st1[2] + st1[3]);
        atomicAdd(&gnstat[h * 2 + 1], st1[8] + st1[9] + st1[10] + st1[11]);
    }
}

// ---------------------------------------------------------------- K9: GN apply + merge GEMM + skip (per batch)
__global__ __launch_bounds__(128) void gn_merge_kernel(
    const u16* __restrict__ A, const float* __restrict__ gnstat,
    const float* __restrict__ gn_g, const float* __restrict__ gn_b,
    const float* __restrict__ mw, const float* __restrict__ uskip, float* __restrict__ D)
{
    __shared__ float sx[16][516];
    __shared__ float sm[8], siv[8];
    int t = threadIdx.x;
    int row0 = blockIdx.x * 16;        // grid 2048
    if (t < 8) {
        const float Ninv = 1.f / 2097152.f;   // 128*256*64
        float s1 = gnstat[t * 2], s2 = gnstat[t * 2 + 1];
        float m = s1 * Ninv;
        float var = s2 * Ninv - m * m;
        sm[t] = m; siv[t] = rsqrtf(var + 1e-5f);
    }
    __syncthreads();
    for (int r = 0; r < 16; ++r)
        for (int d = t; d < 512; d += 128) {
            float x = b2f(A[(size_t)(row0 + r) * 512 + d]);
            int h = d >> 6;
            sx[r][d] = (x - sm[h]) * siv[h] * gn_g[d] + gn_b[d];
        }
    __syncthreads();
    float a0[16], a1[16];
    #pragma unroll
    for (int r = 0; r < 16; ++r) { a0[r] = 0.f; a1[r] = 0.f; }
    #pragma unroll 2
    for (int i = 0; i < 512; ++i) {
        float w0 = mw[i * 256 + t], w1 = mw[i * 256 + t + 128];
        #pragma unroll
        for (int r = 0; r < 16; ++r) {
            float xv = sx[r][i];
            a0[r] = fmaf(xv, w0, a0[r]);
            a1[r] = fmaf(xv, w1, a1[r]);
        }
    }
    #pragma unroll
    for (int r = 0; r < 16; ++r) {
        size_t base = (size_t)(row0 + r) * 256;
        D[base + t]       = a0[r] + uskip[base + t];
        D[base + t + 128] = a1[r] + uskip[base + t + 128];
    }
}

// ---------------------------------------------------------------- K10: final GEMM (per batch)
__global__ __launch_bounds__(128) void out_gemm_kernel(
    const float* __restrict__ D, const float* __restrict__ ow, float* __restrict__ out)
{
    __shared__ float sx[16][260];
    int t = threadIdx.x;
    int row0 = blockIdx.x * 16;        // grid 2048
    for (int r = 0; r < 16; ++r)
        for (int d = t; d < 256; d += 128) sx[r][d] = D[(size_t)(row0 + r) * 256 + d];
    __syncthreads();
    float a0[16], a1[16];
    #pragma unroll
    for (int r = 0; r < 16; ++r) { a0[r] = 0.f; a1[r] = 0.f; }
    #pragma unroll 2
    for (int i = 0; i < 256; ++i) {
        float w0 = ow[i * 256 + t], w1 = ow[i * 256 + t + 128];
        #pragma unroll
        for (int r = 0; r < 16; ++r) {
            float xv = sx[r][i];
            a0[r] = fmaf(xv, w0, a0[r]);
            a1[r] = fmaf(xv, w1, a1[r]);
        }
    }
    #pragma unroll
    for (int r = 0; r < 16; ++r) {
        size_t base = (size_t)(row0 + r) * 256;
        out[base + t]       = a0[r];
        out[base + t + 128] = a1[r];
    }
}

__global__ void zero_kernel(float* __restrict__ p, int n) {
    int i = blockIdx.x * blockDim.x + threadIdx.x;
    if (i < n) p[i] = 0.f;
}

// ================================================================ launch
// Workspace layout identical to R3 (74.3 MB, guard 77,856,896 unchanged).
// w1T/w2T (3.93 MB bf16) alias the qlong..klatp pool (dead during cm_mlp;
// re-converted each batch after proj clobbers them).
extern "C" void kernel_launch(void* const* d_in, const int* in_sizes, int n_in,
                              void* d_out, int out_size, void* d_ws, size_t ws_size,
                              hipStream_t stream) {
    if (ws_size < 77856896ULL) return;   // known-good budget from R3

    const float* u        = (const float*)d_in[0];
    const float* lat      = (const float*)d_in[1];
    const float* lon      = (const float*)d_in[2];
    const float* cm_w1    = (const float*)d_in[3];
    const float* cm_b1    = (const float*)d_in[4];
    const float* cm_w2    = (const float*)d_in[5];
    const float* cm_b2    = (const float*)d_in[6];
    const float* long_in_w  = (const float*)d_in[7];
    const float* long_ln_g  = (const float*)d_in[8];
    const float* long_ln_b  = (const float*)d_in[9];
    const float* long_fc1_w = (const float*)d_in[10];
    const float* long_fc1_b = (const float*)d_in[11];
    const float* long_fc2_w = (const float*)d_in[12];
    const float* long_fc2_b = (const float*)d_in[13];
    const float* lat_in_w   = (const float*)d_in[14];
    const float* lat_ln_g   = (const float*)d_in[15];
    const float* lat_ln_b   = (const float*)d_in[16];
    const float* lat_fc1_w  = (const float*)d_in[17];
    const float* lat_fc1_b  = (const float*)d_in[18];
    const float* lat_fc2_w  = (const float*)d_in[19];
    const float* lat_fc2_b  = (const float*)d_in[20];
    const float* klong_q_w  = (const float*)d_in[21];
    const float* klong_k_w  = (const float*)d_in[22];
    const float* klat_q_w   = (const float*)d_in[23];
    const float* klat_k_w   = (const float*)d_in[24];
    const float* pe_long_freq = (const float*)d_in[25];
    const float* pe_long_w    = (const float*)d_in[26];
    const float* pe_lat_freq  = (const float*)d_in[27];
    const float* pe_lat_w     = (const float*)d_in[28];
    const float* gn_g    = (const float*)d_in[29];
    const float* gn_b    = (const float*)d_in[30];
    const float* merge_w = (const float*)d_in[31];
    const float* out_w   = (const float*)d_in[32];
    float* out = (float*)d_out;

    char* base = (char*)d_ws;
    u16*  vA   = (u16*)base;                          // v then A (bf16)
    char* reg1 = base + 33554432;
    u16*  uu   = (u16*)reg1;                          // bf16
    u16*  tmp1 = (u16*)reg1;                          // bf16 (after uu dead)
    float* D   = (float*)reg1;                        // fp32 (after tmp1 dead)
    float* modlong = (float*)(base + 67108864);       // 524,288 f
    float* modlat  = modlong + 524288;                // 131,072 f
    float* Mlong   = modlat + 131072;                 // 65,536 f
    float* Mlat    = Mlong + 65536;                   // 32,768 f
    float* ulong   = Mlat + 32768;                    // 65,536 f
    float* ulat    = ulong + 65536;                   // 32,768 f
    float* qlong   = ulat + 32768;                    // 393,216 f
    float* klongp  = qlong + 393216;                  // 393,216 f
    float* qlat    = klongp + 393216;                 // 196,608 f
    float* klatp   = qlat + 196608;                   // 196,608 f
    float* KlongT  = klatp + 196608;                  // 524,288 f
    float* Klat    = KlongT + 524288;                 // 131,072 f
    float* gnstat  = Klat + 131072;                   // 32 f
    u16* w1T = (u16*)qlong;                           // 786,432 B  (alias, dead at cm_mlp time)
    u16* w2T = (u16*)klongp;                          // 3,145,728 B (alias: klongp+qlat+klatp)

    zero_kernel<<<1, 32, 0, stream>>>(gnstat, 32);
    bessel_kernel<<<256, 256, 0, stream>>>(lon, 256, pe_long_freq, 64, pe_long_w, modlong, 1);
    bessel_kernel<<<128, 128, 0, stream>>>(lat, 128, pe_lat_freq, 32, pe_lat_w, modlat, 0);

    for (int b = 0; b < 2; ++b) {
        const float* u_b  = u + (size_t)b * 32768 * 256;
        float* uskip_b    = out + (size_t)b * 8388608;
        float* gnstat_b   = gnstat + b * 16;

        conv_w1t_kernel<<<1536, 256, 0, stream>>>(cm_w1, w1T);
        conv_w2t_kernel<<<6144, 256, 0, stream>>>(cm_w2, w2T);
        cm_mlp_mfma_kernel<<<2048, 256, 0, stream>>>(u_b, w1T, cm_b1, w2T, cm_b2,
                                                     vA, uu, uskip_b);
        mean_over_lat_kernel<<<256, 256, 0, stream>>>(uu, Mlong);
        mean_over_lon_kernel<<<128, 256, 0, stream>>>(uu, Mlat);
        pool_mlp_kernel<<<256, 256, 0, stream>>>(Mlong, long_in_w, long_ln_g, long_ln_b,
                                                 long_fc1_w, long_fc1_b, long_fc2_w, long_fc2_b,
                                                 nullptr, ulong);
        pool_mlp_kernel<<<128, 256, 0, stream>>>(Mlat, lat_in_w, lat_ln_g, lat_ln_b,
                                                 lat_fc1_w, lat_fc1_b, lat_fc2_w, lat_fc2_b,
                                                 lat, ulat);
        proj_kernel<<<256, 256, 0, stream>>>(ulong, klong_q_w, qlong);     // clobbers w1T (dead)
        proj_kernel<<<256, 256, 0, stream>>>(ulong, klong_k_w, klongp);    // clobbers w2T (dead)
        proj_kernel<<<128, 256, 0, stream>>>(ulat, klat_q_w, qlat);
        proj_kernel<<<128, 256, 0, stream>>>(ulat, klat_k_w, klatp);
        kmat_long_kernel<<<2048, 256, 0, stream>>>(qlong, klongp, modlong, KlongT);
        kmat_lat_kernel<<<1024, 128, 0, stream>>>(qlat, klatp, modlat, lat, Klat);
        einsum1_kernel<<<512, 256, 0, stream>>>(Klat, vA, tmp1);           // tmp1 over uu (dead)
        einsum2_kernel<<<1024, 256, 0, stream>>>(tmp1, KlongT, vA, gnstat_b); // A over v (dead)
        gn_merge_kernel<<<2048, 128, 0, stream>>>(vA, gnstat_b, gn_g, gn_b, merge_w,
                                                  uskip_b, D);             // D over tmp1 (dead)
        out_gemm_kernel<<<2048, 128, 0, stream>>>(D, out_w, out + (size_t)b * 8388608);
    }
}

// Round 5
// 3026.565 us; speedup vs baseline: 3.0688x; 1.7216x over previous
//
#include <hip/hip_runtime.h>
#include <math.h>
#include <stdint.h>

#define NLAT 128
#define NLON 256
#define PI_F 3.14159265358979323846f
#define TWO_PI_F 6.28318530717958647692f

typedef unsigned short u16;
typedef __attribute__((ext_vector_type(8))) short bf16x8;
typedef __attribute__((ext_vector_type(4))) float f32x4;

__device__ __forceinline__ u16 f2b(float f) {
    union { float f; uint32_t u; } v; v.f = f;
    uint32_t r = v.u + 0x7fffu + ((v.u >> 16) & 1u);
    return (u16)(r >> 16);
}
__device__ __forceinline__ float b2f(u16 u) {
    union { uint32_t u; float f; } v; v.u = ((uint32_t)u) << 16;
    return v.f;
}
__device__ __forceinline__ ushort4 pack4(float a, float b, float c, float d) {
    ushort4 r; r.x = f2b(a); r.y = f2b(b); r.z = f2b(c); r.w = f2b(d); return r;
}
__device__ __forceinline__ float gelu_tanh(float x) {
    float x3 = x * x * x;
    return 0.5f * x * (1.0f + tanhf(0.7978845608028654f * (x + 0.044715f * x3)));
}
__device__ __forceinline__ float leaky(float x) { return x >= 0.0f ? x : 0.2f * x; }

__device__ __forceinline__ float lat_weight(const float* __restrict__ lat, int i, int n) {
    float w = cosf(lat[i]);
    if ((i == 0 || i == n - 1) && w < 0.001f) {
        float dlat = lat[1] - lat[0];
        float s = sinf(dlat * 0.25f);
        w = s * s / sinf(dlat * 0.5f);
    }
    return w;
}

// ================================================================ generic 128x128 MFMA GEMM
// A: [M][KD] (bf16 K-major, or fp32 if AF32). B: [N][KD] bf16 (n-major rows).
// EPI: 0 gelu->bf16 O0[row][1536]; 1 split v/uu/uskip; 2 +bias2+uskip -> fp32 O0[row][256];
//      3 plain fp32 O0[row][256].
template<int KD, int EPI, bool AF32>
__global__ __launch_bounds__(256) void gemm128_kernel(
    const void* __restrict__ Aptr, const u16* __restrict__ B,
    const float* __restrict__ bias, const float* __restrict__ uskip,
    void* __restrict__ O0, void* __restrict__ O1, void* __restrict__ O2)
{
    __shared__ __align__(16) u16 sA[128][40];
    __shared__ __align__(16) u16 sB[128][40];
    const int t = threadIdx.x;
    const int lane = t & 63, w = t >> 6;
    const int ln = lane & 15, q = lane >> 4;
    const int wr = w >> 1, wc = w & 1;
    const int row0 = blockIdx.x * 128;
    const int col0 = blockIdx.y * 128;
    const int sr = t >> 1, sh = t & 1;

    f32x4 acc[16];
    #pragma unroll
    for (int i = 0; i < 16; ++i) acc[i] = (f32x4){0.f, 0.f, 0.f, 0.f};

    for (int k0 = 0; k0 < KD; k0 += 32) {
        __syncthreads();
        if (AF32) {
            const float* Ag = (const float*)Aptr + (size_t)(row0 + sr) * KD + k0 + sh * 16;
            float4 f0 = *(const float4*)Ag;
            float4 f1 = *(const float4*)(Ag + 4);
            float4 f2 = *(const float4*)(Ag + 8);
            float4 f3 = *(const float4*)(Ag + 12);
            *(ushort4*)&sA[sr][sh * 16]     = pack4(f0.x, f0.y, f0.z, f0.w);
            *(ushort4*)&sA[sr][sh * 16 + 4] = pack4(f1.x, f1.y, f1.z, f1.w);
            *(ushort4*)&sA[sr][sh * 16 + 8] = pack4(f2.x, f2.y, f2.z, f2.w);
            *(ushort4*)&sA[sr][sh * 16 +12] = pack4(f3.x, f3.y, f3.z, f3.w);
        } else {
            const u16* Ag = (const u16*)Aptr + (size_t)(row0 + sr) * KD + k0 + sh * 16;
            *(uint4*)&sA[sr][sh * 16]     = *(const uint4*)Ag;
            *(uint4*)&sA[sr][sh * 16 + 8] = *(const uint4*)(Ag + 8);
        }
        {
            const u16* Bg = B + (size_t)(col0 + sr) * KD + k0 + sh * 16;
            *(uint4*)&sB[sr][sh * 16]     = *(const uint4*)Bg;
            *(uint4*)&sB[sr][sh * 16 + 8] = *(const uint4*)(Bg + 8);
        }
        __syncthreads();
        bf16x8 af[4], bf[4];
        #pragma unroll
        for (int x = 0; x < 4; ++x) af[x] = *(const bf16x8*)&sA[wr * 64 + x * 16 + ln][q * 8];
        #pragma unroll
        for (int x = 0; x < 4; ++x) bf[x] = *(const bf16x8*)&sB[wc * 64 + x * 16 + ln][q * 8];
        #pragma unroll
        for (int rt = 0; rt < 4; ++rt)
            #pragma unroll
            for (int ct = 0; ct < 4; ++ct)
                acc[rt * 4 + ct] = __builtin_amdgcn_mfma_f32_16x16x32_bf16(af[rt], bf[ct], acc[rt * 4 + ct], 0, 0, 0);
    }

    #pragma unroll
    for (int rt = 0; rt < 4; ++rt)
        #pragma unroll
        for (int ct = 0; ct < 4; ++ct) {
            int col = col0 + wc * 64 + ct * 16 + ln;
            float bv = (EPI == 3) ? 0.f : bias[col];
            #pragma unroll
            for (int r = 0; r < 4; ++r) {
                int row = row0 + wr * 64 + rt * 16 + q * 4 + r;
                float x = acc[rt * 4 + ct][r] + bv;
                if (EPI == 0) {
                    ((u16*)O0)[(size_t)row * 1536 + col] = f2b(gelu_tanh(x));
                } else if (EPI == 1) {
                    if (col < 512)      ((u16*)O0)[(size_t)row * 512 + col] = f2b(x);
                    else if (col < 768) ((u16*)O1)[(size_t)row * 256 + col - 512] = f2b(x);
                    else                ((float*)O2)[(size_t)row * 256 + col - 768] = x;
                } else if (EPI == 2) {
                    ((float*)O0)[(size_t)row * 256 + col] = x + uskip[(size_t)row * 256 + col];
                } else {
                    ((float*)O0)[(size_t)row * 256 + col] = x;
                }
            }
        }
}

// ---------------------------------------------------------------- W conversions
__global__ void conv_w1t_kernel(const float* __restrict__ w1, u16* __restrict__ w1t) {
    int idx = blockIdx.x * 256 + threadIdx.x;       // grid 1536: w1t[1536][256]
    int j = idx >> 8, i = idx & 255;
    w1t[idx] = f2b(w1[(size_t)i * 1536 + j]);
}
__global__ void conv_w2t_kernel(const float* __restrict__ w2, u16* __restrict__ w2t) {
    int k = blockIdx.x / 6, s = blockIdx.x % 6;     // grid 6144: w2t[1024][1536]
    int i = s * 256 + threadIdx.x;
    w2t[(size_t)k * 1536 + i] = f2b(w2[(size_t)i * 1024 + k]);
}
__global__ void conv_owt_kernel(const float* __restrict__ ow, u16* __restrict__ owt) {
    int n = blockIdx.x, k = threadIdx.x;            // owt[256][256]
    owt[(size_t)n * 256 + k] = f2b(ow[(size_t)k * 256 + n]);
}

// ---------------------------------------------------------------- K1 fallback: fused cm MLP (R4, verified)
__global__ __launch_bounds__(256, 2) void cm_mlp_mfma_kernel(
    const float* __restrict__ u, const u16* __restrict__ w1t, const float* __restrict__ b1,
    const u16* __restrict__ w2t, const float* __restrict__ b2,
    u16* __restrict__ v, u16* __restrict__ uu, float* __restrict__ uskip)
{
    __shared__ __align__(16) u16 sA[16][264];
    __shared__ __align__(16) u16 sH[16][520];
    const int t = threadIdx.x;
    const int lane = t & 63, w = t >> 6;
    const int ln = lane & 15, q = lane >> 4;
    const int row0 = blockIdx.x * 16;

    for (int x = t; x < 1024; x += 256) {
        int r = x >> 6, c0 = (x & 63) * 4;
        float4 xx = *(const float4*)(u + (size_t)(row0 + r) * 256 + c0);
        sA[r][c0 + 0] = f2b(xx.x); sA[r][c0 + 1] = f2b(xx.y);
        sA[r][c0 + 2] = f2b(xx.z); sA[r][c0 + 3] = f2b(xx.w);
    }
    f32x4 c2[16];
    #pragma unroll
    for (int i = 0; i < 16; ++i) c2[i] = (f32x4){0.f, 0.f, 0.f, 0.f};

    for (int jj = 0; jj < 3; ++jj) {
        __syncthreads();
        f32x4 c1[8];
        #pragma unroll
        for (int i = 0; i < 8; ++i) c1[i] = (f32x4){0.f, 0.f, 0.f, 0.f};
        {
            const u16* w1p = w1t + (size_t)(jj * 512 + w * 128 + ln) * 256 + q * 8;
            #pragma unroll
            for (int k0 = 0; k0 < 256; k0 += 32) {
                bf16x8 a = *(const bf16x8*)&sA[ln][k0 + q * 8];
                #pragma unroll
                for (int nt = 0; nt < 8; ++nt) {
                    bf16x8 b = *(const bf16x8*)(w1p + (size_t)nt * 16 * 256 + k0);
                    c1[nt] = __builtin_amdgcn_mfma_f32_16x16x32_bf16(a, b, c1[nt], 0, 0, 0);
                }
            }
        }
        #pragma unroll
        for (int nt = 0; nt < 8; ++nt) {
            int col = w * 128 + nt * 16 + ln;
            float bias = b1[jj * 512 + col];
            #pragma unroll
            for (int r = 0; r < 4; ++r)
                sH[q * 4 + r][col] = f2b(gelu_tanh(c1[nt][r] + bias));
        }
        __syncthreads();
        const u16* w2p = w2t + (size_t)(w * 256 + ln) * 1536 + jj * 512 + q * 8;
        #pragma unroll 2
        for (int k0 = 0; k0 < 512; k0 += 32) {
            bf16x8 a = *(const bf16x8*)&sH[ln][k0 + q * 8];
            #pragma unroll
            for (int nt = 0; nt < 16; ++nt) {
                bf16x8 b = *(const bf16x8*)(w2p + (size_t)nt * 16 * 1536 + k0);
                c2[nt] = __builtin_amdgcn_mfma_f32_16x16x32_bf16(a, b, c2[nt], 0, 0, 0);
            }
        }
    }
    #pragma unroll
    for (int nt = 0; nt < 16; ++nt) {
        int col = w * 256 + nt * 16 + ln;
        float bias = b2[col];
        #pragma unroll
        for (int r = 0; r < 4; ++r) {
            int row = row0 + q * 4 + r;
            float val = c2[nt][r] + bias;
            if (col < 512)      v[(size_t)row * 512 + col] = f2b(val);
            else if (col < 768) uu[(size_t)row * 256 + (col - 512)] = f2b(val);
            else                uskip[(size_t)row * 256 + (col - 768)] = val;
        }
    }
}

// ---------------------------------------------------------------- K2: means of uu
__global__ void mean_over_lat_kernel(const u16* __restrict__ uu, float* __restrict__ Mlong) {
    int l = blockIdx.x, d = threadIdx.x;
    float s = 0.f;
    for (int i = 0; i < NLAT; ++i) s += b2f(uu[((size_t)i * NLON + l) * 256 + d]);
    Mlong[(size_t)l * 256 + d] = s * (1.0f / NLAT);
}
__global__ void mean_over_lon_kernel(const u16* __restrict__ uu, float* __restrict__ Mlat) {
    int i = blockIdx.x, d = threadIdx.x;
    const u16* p = uu + (size_t)i * NLON * 256 + d;
    float s = 0.f;
    for (int l = 0; l < NLON; ++l) s += b2f(p[(size_t)l * 256]);
    Mlat[(size_t)i * 256 + d] = s * (1.0f / NLON);
}

__device__ float block_sum256(float x, float* red) {
    #pragma unroll
    for (int o = 32; o > 0; o >>= 1) x += __shfl_down(x, o, 64);
    int wid = threadIdx.x >> 6, lane = threadIdx.x & 63;
    if (lane == 0) red[wid] = x;
    __syncthreads();
    float s = red[0] + red[1] + red[2] + red[3];
    __syncthreads();
    return s;
}

// ---------------------------------------------------------------- K3: pool MLP
__global__ __launch_bounds__(256) void pool_mlp_kernel(
    const float* __restrict__ xin, const float* __restrict__ in_w,
    const float* __restrict__ ln_g, const float* __restrict__ ln_b,
    const float* __restrict__ fc1_w, const float* __restrict__ fc1_b,
    const float* __restrict__ fc2_w, const float* __restrict__ fc2_b,
    const float* __restrict__ lat, float* __restrict__ out)
{
    __shared__ float sx[256], sy[256], sg[256], red[4];
    int row = blockIdx.x, t = threadIdx.x;
    sx[t] = xin[(size_t)row * 256 + t];
    __syncthreads();
    float acc = 0.f;
    #pragma unroll 4
    for (int i = 0; i < 256; ++i) acc = fmaf(sx[i], in_w[i * 256 + t], acc);
    if (lat) acc *= lat_weight(lat, row, NLAT);
    float m = block_sum256(acc, red) * (1.f / 256.f);
    float var = block_sum256(acc * acc, red) * (1.f / 256.f) - m * m;
    float xn = (acc - m) * rsqrtf(var + 1e-5f) * ln_g[t] + ln_b[t];
    sy[t] = xn;
    __syncthreads();
    float h1 = fc1_b[t], h2 = fc1_b[t + 256];
    #pragma unroll 4
    for (int i = 0; i < 256; ++i) {
        float s = sy[i];
        h1 = fmaf(s, fc1_w[i * 512 + t], h1);
        h2 = fmaf(s, fc1_w[i * 512 + 256 + t], h2);
    }
    float g = h1 * gelu_tanh(h2);
    sg[t] = g;
    __syncthreads();
    float o = fc2_b[t];
    #pragma unroll 4
    for (int i = 0; i < 256; ++i) o = fmaf(sg[i], fc2_w[i * 256 + t], o);
    out[(size_t)row * 256 + t] = o;
}

// ---------------------------------------------------------------- K4: bessel
__global__ void bessel_kernel(const float* __restrict__ coord, int n,
                              const float* __restrict__ freq, int nf,
                              const float* __restrict__ w, float* __restrict__ mod,
                              int periodic)
{
    int i = blockIdx.x, j = threadIdx.x;
    float d = fabsf(coord[j] - coord[i]);
    if (periodic) d = fminf(d, TWO_PI_F - d);
    float acc[8];
    #pragma unroll
    for (int h = 0; h < 8; ++h) acc[h] = 0.f;
    bool big = d > 1e-6f;
    float inv = big ? 1.f / d : 0.f;
    for (int k = 0; k < nf; ++k) {
        float f = freq[k];
        float basis = big ? sinf(f * d) * inv : f;
        #pragma unroll
        for (int h = 0; h < 8; ++h) acc[h] = fmaf(basis, w[k * 8 + h], acc[h]);
    }
    #pragma unroll
    for (int h = 0; h < 8; ++h) mod[((size_t)h * n + i) * n + j] = acc[h];
}

// ---------------------------------------------------------------- K5: projections
__global__ __launch_bounds__(256) void proj_kernel(const float* __restrict__ x,
                                                   const float* __restrict__ w,
                                                   float* __restrict__ c)
{
    __shared__ float sx[256];
    int row = blockIdx.x, t = threadIdx.x;
    sx[t] = x[(size_t)row * 256 + t];
    __syncthreads();
    for (int jj = 0; jj < 6; ++jj) {
        int j = t + jj * 256;
        float acc = 0.f;
        #pragma unroll 4
        for (int i = 0; i < 256; ++i) acc = fmaf(sx[i], w[(size_t)i * 1536 + j], acc);
        c[(size_t)row * 1536 + j] = acc;
    }
}

// ---------------------------------------------------------------- K6a: k_long -> KlongA[h][l][m] bf16 (K-major)
__global__ __launch_bounds__(256) void kmat_long_kernel(
    const float* __restrict__ q, const float* __restrict__ kp,
    const float* __restrict__ mod, u16* __restrict__ KA)
{
    int blk = blockIdx.x;              // h*256 + l   (grid 2048)
    int l = blk & 255, h = blk >> 8;
    __shared__ float sq[192];
    int t = threadIdx.x;
    if (t < 192) sq[t] = q[(size_t)l * 1536 + h * 192 + t];
    __syncthreads();
    const float* kpp = kp + (size_t)t * 1536 + h * 192;
    float acc = 0.f;
    #pragma unroll 4
    for (int c = 0; c < 192; ++c) acc = fmaf(kpp[c], sq[c], acc);
    float mv = mod[((size_t)h * 256 + l) * 256 + t];
    float val = leaky(acc * mv) * (TWO_PI_F / 256.f);
    KA[((size_t)h * 256 + l) * 256 + t] = f2b(val);
}

// ---------------------------------------------------------------- K6b: k_lat -> KlatA[h][i][j] bf16 (K-major)
__global__ __launch_bounds__(128) void kmat_lat_kernel(
    const float* __restrict__ q, const float* __restrict__ kp,
    const float* __restrict__ mod, const float* __restrict__ lat, u16* __restrict__ KA)
{
    int blk = blockIdx.x;              // h*128 + i   (grid 1024)
    int i = blk & 127, h = blk >> 7;
    __shared__ float sq[192];
    int t = threadIdx.x;
    for (int c = t; c < 192; c += 128) sq[c] = q[(size_t)i * 1536 + h * 192 + c];
    __syncthreads();
    const float* kpp = kp + (size_t)t * 1536 + h * 192;
    float acc = 0.f;
    #pragma unroll 4
    for (int c = 0; c < 192; ++c) acc = fmaf(kpp[c], sq[c], acc);
    float mv = mod[((size_t)h * 128 + i) * 128 + t];
    float wl = lat_weight(lat, t, NLAT);
    float val = leaky(acc * mv) * wl * (PI_F / 128.f);
    KA[((size_t)h * 128 + i) * 128 + t] = f2b(val);
}

// ---------------------------------------------------------------- K7: einsum1 MFMA (per batch)
// tmp1[h,i,m,c] = sum_j KlatA[h,i,j] * v[j,m,h*64+c]; block=(h,m), D[i=128, c=64], K=j=128
__global__ __launch_bounds__(256) void einsum1_kernel(
    const u16* __restrict__ KlatA, const u16* __restrict__ v, u16* __restrict__ tmp1)
{
    int blk = blockIdx.x;              // h*256 + m (grid 2048)
    int m = blk & 255, h = blk >> 8;
    __shared__ __align__(16) u16 sV[64][136];   // [c][j], rows 272 B (16-aligned)
    const int t = threadIdx.x;
    const int lane = t & 63, w = t >> 6;
    const int ln = lane & 15, q = lane >> 4;

    {   // transpose-stage v slice [j=128][c=64] -> sV[c][j]
        int j = t >> 1, c0 = (t & 1) * 32;
        const u16* vp = v + ((size_t)j * 256 + m) * 512 + h * 64 + c0;
        union { uint4 q4[4]; u16 s[32]; } buf;
        buf.q4[0] = *(const uint4*)(vp);
        buf.q4[1] = *(const uint4*)(vp + 8);
        buf.q4[2] = *(const uint4*)(vp + 16);
        buf.q4[3] = *(const uint4*)(vp + 24);
        #pragma unroll
        for (int cc = 0; cc < 32; ++cc) sV[c0 + cc][j] = buf.s[cc];
    }
    __syncthreads();

    f32x4 acc[8];
    #pragma unroll
    for (int i = 0; i < 8; ++i) acc[i] = (f32x4){0.f, 0.f, 0.f, 0.f};
    const u16* ka = KlatA + (size_t)h * 128 * 128;
    for (int ch = 0; ch < 4; ++ch) {
        int j0 = ch * 32;
        bf16x8 b = *(const bf16x8*)&sV[w * 16 + ln][j0 + q * 8];
        #pragma unroll
        for (int it = 0; it < 8; ++it) {
            bf16x8 a = *(const bf16x8*)(ka + (size_t)(it * 16 + ln) * 128 + j0 + q * 8);
            acc[it] = __builtin_amdgcn_mfma_f32_16x16x32_bf16(a, b, acc[it], 0, 0, 0);
        }
    }
    int c = w * 16 + ln;
    #pragma unroll
    for (int it = 0; it < 8; ++it)
        #pragma unroll
        for (int r = 0; r < 4; ++r) {
            int i = it * 16 + q * 4 + r;
            tmp1[(((size_t)h * 128 + i) * 256 + m) * 64 + c] = f2b(acc[it][r]);
        }
}

// ---------------------------------------------------------------- K8: einsum2 MFMA + GN stats (per batch)
// Aout[(i*256+l)*512 + h*64+c] = sum_m KlongA[h,l,m]*tmp1[h,i,m,c]; block=(h,i), D[l=256,c=64], K=m=256
__global__ __launch_bounds__(256) void einsum2_kernel(
    const u16* __restrict__ tmp1, const u16* __restrict__ KlongA,
    u16* __restrict__ Aout, float* __restrict__ gnstat)
{
    int blk = blockIdx.x;              // h*128 + i (grid 1024)
    int i = blk & 127, h = blk >> 7;
    __shared__ __align__(16) u16 sT[64][264];   // [c][m], rows 528 B (16-aligned)
    __shared__ float red2[8];
    const int t = threadIdx.x;
    const int lane = t & 63, w = t >> 6;
    const int ln = lane & 15, q = lane >> 4;

    {   // transpose-stage tmp1 slice [m=256][c=64] -> sT[c][m]
        const u16* tp = tmp1 + (((size_t)h * 128 + i) * 256 + t) * 64;
        union { uint4 q4[8]; u16 s[64]; } buf;
        #pragma unroll
        for (int x = 0; x < 8; ++x) buf.q4[x] = *(const uint4*)(tp + x * 8);
        #pragma unroll
        for (int cc = 0; cc < 64; ++cc) sT[cc][t] = buf.s[cc];
    }
    __syncthreads();

    f32x4 acc[16];
    #pragma unroll
    for (int x = 0; x < 16; ++x) acc[x] = (f32x4){0.f, 0.f, 0.f, 0.f};
    const u16* ka = KlongA + (size_t)h * 256 * 256;
    for (int ch = 0; ch < 8; ++ch) {
        int m0 = ch * 32;
        bf16x8 bf[4];
        #pragma unroll
        for (int ct = 0; ct < 4; ++ct) bf[ct] = *(const bf16x8*)&sT[ct * 16 + ln][m0 + q * 8];
        #pragma unroll
        for (int lt = 0; lt < 4; ++lt) {
            bf16x8 a = *(const bf16x8*)(ka + (size_t)(w * 64 + lt * 16 + ln) * 256 + m0 + q * 8);
            #pragma unroll
            for (int ct = 0; ct < 4; ++ct)
                acc[lt * 4 + ct] = __builtin_amdgcn_mfma_f32_16x16x32_bf16(a, bf[ct], acc[lt * 4 + ct], 0, 0, 0);
        }
    }
    float lsum = 0.f, lsq = 0.f;
    #pragma unroll
    for (int lt = 0; lt < 4; ++lt)
        #pragma unroll
        for (int ct = 0; ct < 4; ++ct) {
            int c = ct * 16 + ln;
            #pragma unroll
            for (int r = 0; r < 4; ++r) {
                int l = w * 64 + lt * 16 + q * 4 + r;
                float val = acc[lt * 4 + ct][r];
                Aout[((size_t)i * 256 + l) * 512 + h * 64 + c] = f2b(val);
                lsum += val; lsq += val * val;
            }
        }
    #pragma unroll
    for (int o = 32; o > 0; o >>= 1) {
        lsum += __shfl_down(lsum, o, 64);
        lsq  += __shfl_down(lsq, o, 64);
    }
    if ((t & 63) == 0) { red2[w] = lsum; red2[4 + w] = lsq; }
    __syncthreads();
    if (t == 0) {
        atomicAdd(&gnstat[h * 2],     red2[0] + red2[1] + red2[2] + red2[3]);
        atomicAdd(&gnstat[h * 2 + 1], red2[4] + red2[5] + red2[6] + red2[7]);
    }
}

// ---------------------------------------------------------------- K9: fold GN into merge weights (per batch)
// Wp[j][k] = s_k*mw[k][j] bf16; bias2[j] = sum_k t_k*mw[k][j]
__global__ __launch_bounds__(256) void gn_fold_kernel(
    const float* __restrict__ gnstat, const float* __restrict__ gn_g, const float* __restrict__ gn_b,
    const float* __restrict__ mw, u16* __restrict__ Wp, float* __restrict__ bias2)
{
    __shared__ float red[4];
    int j = blockIdx.x, t = threadIdx.x;
    const float Ninv = 1.f / 2097152.f;   // 128*256*64
    float partial = 0.f;
    for (int k = t; k < 512; k += 256) {
        int h = k >> 6;
        float m = gnstat[h * 2] * Ninv;
        float var = gnstat[h * 2 + 1] * Ninv - m * m;
        float siv = rsqrtf(var + 1e-5f);
        float s = siv * gn_g[k];
        float tt = gn_b[k] - m * s;
        float wv = mw[(size_t)k * 256 + j];
        Wp[(size_t)j * 512 + k] = f2b(s * wv);
        partial += tt * wv;
    }
    float tot = block_sum256(partial, red);
    if (t == 0) bias2[j] = tot;
}

__global__ void zero_kernel(float* __restrict__ p, int n) {
    int i = blockIdx.x * blockDim.x + threadIdx.x;
    if (i < n) p[i] = 0.f;
}

// ================================================================ launch
extern "C" void kernel_launch(void* const* d_in, const int* in_sizes, int n_in,
                              void* d_out, int out_size, void* d_ws, size_t ws_size,
                              hipStream_t stream) {
    if (ws_size < 77856896ULL) return;   // known-good minimum from R3/R4
    const bool BIG = (ws_size >= 184549376ULL);  // de-fused cm path needs 96MB hidden

    const float* u        = (const float*)d_in[0];
    const float* lat      = (const float*)d_in[1];
    const float* lon      = (const float*)d_in[2];
    const float* cm_w1    = (const float*)d_in[3];
    const float* cm_b1    = (const float*)d_in[4];
    const float* cm_w2    = (const float*)d_in[5];
    const float* cm_b2    = (const float*)d_in[6];
    const float* long_in_w  = (const float*)d_in[7];
    const float* long_ln_g  = (const float*)d_in[8];
    const float* long_ln_b  = (const float*)d_in[9];
    const float* long_fc1_w = (const float*)d_in[10];
    const float* long_fc1_b = (const float*)d_in[11];
    const float* long_fc2_w = (const float*)d_in[12];
    const float* long_fc2_b = (const float*)d_in[13];
    const float* lat_in_w   = (const float*)d_in[14];
    const float* lat_ln_g   = (const float*)d_in[15];
    const float* lat_ln_b   = (const float*)d_in[16];
    const float* lat_fc1_w  = (const float*)d_in[17];
    const float* lat_fc1_b  = (const float*)d_in[18];
    const float* lat_fc2_w  = (const float*)d_in[19];
    const float* lat_fc2_b  = (const float*)d_in[20];
    const float* klong_q_w  = (const float*)d_in[21];
    const float* klong_k_w  = (const float*)d_in[22];
    const float* klat_q_w   = (const float*)d_in[23];
    const float* klat_k_w   = (const float*)d_in[24];
    const float* pe_long_freq = (const float*)d_in[25];
    const float* pe_long_w    = (const float*)d_in[26];
    const float* pe_lat_freq  = (const float*)d_in[27];
    const float* pe_lat_w     = (const float*)d_in[28];
    const float* gn_g    = (const float*)d_in[29];
    const float* gn_b    = (const float*)d_in[30];
    const float* merge_w = (const float*)d_in[31];
    const float* out_w   = (const float*)d_in[32];
    float* out = (float*)d_out;

    char* base = (char*)d_ws;
    u16*  vA   = (u16*)base;                          // v bf16 (32MB) -> Aout bf16 (32MB)
    char* reg1 = base + 33554432;                     // uu bf16 (16MB) -> tmp1 bf16 (32MB) -> D fp32 (32MB)
    u16*  uu   = (u16*)reg1;
    u16*  tmp1 = (u16*)reg1;
    float* D   = (float*)reg1;
    // small pool (floats from base+64MB); end = 76,940,416 B < 77,856,896 guard
    float* pool    = (float*)(base + 67108864);
    float* modlong = pool;                            // 524288
    float* modlat  = modlong + 524288;                // 131072
    float* Mlong   = modlat + 131072;                 // 65536
    float* Mlat    = Mlong + 65536;                   // 32768
    float* ulong   = Mlat + 32768;                    // 65536
    float* ulat    = ulong + 65536;                   // 32768
    float* qlong   = ulat + 32768;                    // 393216
    float* klongp  = qlong + 393216;                  // 393216
    float* qlat    = klongp + 393216;                 // 196608
    float* klatp   = qlat + 196608;                   // 196608
    float* gnstat  = klatp + 196608;                  // 32
    float* bias2   = gnstat + 32;                     // 256
    u16* KlongA = (u16*)(bias2 + 256);                // 524288 elems (1MB)
    u16* KlatA  = KlongA + 524288;                    // 131072 elems
    u16* Wp     = KlatA + 131072;                     // 131072 elems
    u16* owT    = Wp + 131072;                        // 65536 elems
    // small-path weight aliases (dead at cm time, re-converted per batch)
    u16* w1T = (u16*)qlong;                           // 786,432 B in qlong (1.5MB)
    u16* w2T = (u16*)klongp;                          // 3,145,728 B in klongp+qlat+klatp
    // big-path dedicated regions
    u16* w1Tb   = (u16*)(base + 79691776);            // 786,432 B
    u16* w2Tb   = (u16*)(base + 80478208);            // 3,145,728 B
    u16* hidden = (u16*)(base + 83886080);            // 100,663,296 B (32768x1536 bf16)

    zero_kernel<<<1, 32, 0, stream>>>(gnstat, 32);
    bessel_kernel<<<256, 256, 0, stream>>>(lon, 256, pe_long_freq, 64, pe_long_w, modlong, 1);
    bessel_kernel<<<128, 128, 0, stream>>>(lat, 128, pe_lat_freq, 32, pe_lat_w, modlat, 0);
    conv_owt_kernel<<<256, 256, 0, stream>>>(out_w, owT);
    if (BIG) {
        conv_w1t_kernel<<<1536, 256, 0, stream>>>(cm_w1, w1Tb);
        conv_w2t_kernel<<<6144, 256, 0, stream>>>(cm_w2, w2Tb);
    }

    for (int b = 0; b < 2; ++b) {
        const float* u_b  = u + (size_t)b * 32768 * 256;
        float* uskip_b    = out + (size_t)b * 8388608;
        float* gnstat_b   = gnstat + b * 16;

        if (BIG) {
            // GEMM1: hidden = gelu(u@W1+b1)  [32768 x 1536], K=256
            gemm128_kernel<256, 0, true><<<dim3(256, 12), 256, 0, stream>>>(
                u_b, w1Tb, cm_b1, nullptr, hidden, nullptr, nullptr);
            // GEMM2: hidden@W2+b2 -> v|uu|uskip  [32768 x 1024], K=1536
            gemm128_kernel<1536, 1, false><<<dim3(256, 8), 256, 0, stream>>>(
                hidden, w2Tb, cm_b2, nullptr, vA, uu, uskip_b);
        } else {
            conv_w1t_kernel<<<1536, 256, 0, stream>>>(cm_w1, w1T);
            conv_w2t_kernel<<<6144, 256, 0, stream>>>(cm_w2, w2T);
            cm_mlp_mfma_kernel<<<2048, 256, 0, stream>>>(u_b, w1T, cm_b1, w2T, cm_b2,
                                                         vA, uu, uskip_b);
        }
        mean_over_lat_kernel<<<256, 256, 0, stream>>>(uu, Mlong);
        mean_over_lon_kernel<<<128, 256, 0, stream>>>(uu, Mlat);
        pool_mlp_kernel<<<256, 256, 0, stream>>>(Mlong, long_in_w, long_ln_g, long_ln_b,
                                                 long_fc1_w, long_fc1_b, long_fc2_w, long_fc2_b,
                                                 nullptr, ulong);
        pool_mlp_kernel<<<128, 256, 0, stream>>>(Mlat, lat_in_w, lat_ln_g, lat_ln_b,
                                                 lat_fc1_w, lat_fc1_b, lat_fc2_w, lat_fc2_b,
                                                 lat, ulat);
        proj_kernel<<<256, 256, 0, stream>>>(ulong, klong_q_w, qlong);   // clobbers w1T (dead)
        proj_kernel<<<256, 256, 0, stream>>>(ulong, klong_k_w, klongp);  // clobbers w2T (dead)
        proj_kernel<<<128, 256, 0, stream>>>(ulat, klat_q_w, qlat);
        proj_kernel<<<128, 256, 0, stream>>>(ulat, klat_k_w, klatp);
        kmat_long_kernel<<<2048, 256, 0, stream>>>(qlong, klongp, modlong, KlongA);
        kmat_lat_kernel<<<1024, 128, 0, stream>>>(qlat, klatp, modlat, lat, KlatA);
        einsum1_kernel<<<2048, 256, 0, stream>>>(KlatA, vA, tmp1);       // tmp1 over uu (dead)
        einsum2_kernel<<<1024, 256, 0, stream>>>(tmp1, KlongA, vA, gnstat_b); // Aout over v (dead)
        gn_fold_kernel<<<256, 256, 0, stream>>>(gnstat_b, gn_g, gn_b, merge_w, Wp, bias2);
        // merge: D = GN(Aout)@mw + uskip   [32768 x 256], K=512  (D over tmp1, dead)
        gemm128_kernel<512, 2, false><<<dim3(256, 2), 256, 0, stream>>>(
            vA, Wp, bias2, uskip_b, D, nullptr, nullptr);
        // out: out = D@ow                  [32768 x 256], K=256
        gemm128_kernel<256, 3, true><<<dim3(256, 2), 256, 0, stream>>>(
            D, owT, nullptr, nullptr, out + (size_t)b * 8388608, nullptr, nullptr);
    }
}